// Round 5
// baseline (193.980 us; speedup 1.0000x reference)
//
#include <hip/hip_runtime.h>

#define BS_   4
#define SEQ_  4096
#define DIM_  768
#define NH_   12
#define HD_   64
#define LK_   256

typedef __attribute__((ext_vector_type(8))) short          bf8;
typedef __attribute__((ext_vector_type(4))) short          bf4;
typedef __attribute__((ext_vector_type(8))) unsigned short us8;
typedef __attribute__((ext_vector_type(4))) float          f32x4;

__device__ __forceinline__ unsigned short f2bf(float f) {
  unsigned u = __builtin_bit_cast(unsigned, f);
  u += 0x7fffu + ((u >> 16) & 1u);   // round-to-nearest-even
  return (unsigned short)(u >> 16);
}

__device__ __forceinline__ us8 cvt8(const float* __restrict__ p) {
  const float4 a = *(const float4*)p;
  const float4 b = *(const float4*)(p + 4);
  us8 r;
  r[0] = f2bf(a.x); r[1] = f2bf(a.y); r[2] = f2bf(a.z); r[3] = f2bf(a.w);
  r[4] = f2bf(b.x); r[5] = f2bf(b.y); r[6] = f2bf(b.z); r[7] = f2bf(b.w);
  return r;
}

// K=16 bf16 MFMA: A-frag k-pattern (lane>>4)*4+j matches the swapped-QK^T
// C-row pattern exactly, so softmax'd P feeds PV straight from registers.
__device__ __forceinline__ f32x4 mfma16bf16(bf4 a, bf4 b, f32x4 c) {
#if __has_builtin(__builtin_amdgcn_mfma_f32_16x16x16bf16_1k)
  return __builtin_amdgcn_mfma_f32_16x16x16bf16_1k(a, b, c, 0, 0, 0);
#else
  asm volatile("v_mfma_f32_16x16x16_bf16 %0, %1, %2, %0\n\ts_nop 7\n\ts_nop 7"
               : "+v"(c) : "v"(a), "v"(b));
  return c;
#endif
}

// ---------------------------------------------------------------------------
// Pool: pooled[b,l,d] = (1/16) sum_w keep(b,l*16+w) * x[b,l*16+w,d]  (bf16 out)
// ---------------------------------------------------------------------------
__global__ __launch_bounds__(256) void pool_kernel(
    const float* __restrict__ key, const float* __restrict__ value,
    const float* __restrict__ mask,
    unsigned short* __restrict__ pk, unsigned short* __restrict__ pv,
    float* __restrict__ frac)
{
  const int blk = blockIdx.x;          // 0..1023
  const int b = blk >> 8;
  const int l = blk & 255;
  const int tid = threadIdx.x;
  __shared__ float keep[16];
  if (tid < 16) keep[tid] = (mask[b * SEQ_ + l * 16 + tid] >= 0.f) ? 1.f : 0.f;
  __syncthreads();
  float ak0 = 0.f, ak1 = 0.f, ak2 = 0.f, av0 = 0.f, av1 = 0.f, av2 = 0.f;
  #pragma unroll 1
  for (int w = 0; w < 16; ++w) {
    if (keep[w] != 0.f) {              // block-uniform branch
      const size_t row = (size_t)(b * SEQ_ + l * 16 + w) * DIM_;
      const float* kr = key + row;
      const float* vr = value + row;
      ak0 += kr[tid]; ak1 += kr[tid + 256]; ak2 += kr[tid + 512];
      av0 += vr[tid]; av1 += vr[tid + 256]; av2 += vr[tid + 512];
    }
  }
  const size_t o = (size_t)(b * LK_ + l) * DIM_;
  const float s = 1.f / 16.f;
  pk[o + tid] = f2bf(ak0 * s); pk[o + tid + 256] = f2bf(ak1 * s); pk[o + tid + 512] = f2bf(ak2 * s);
  pv[o + tid] = f2bf(av0 * s); pv[o + tid + 256] = f2bf(av1 * s); pv[o + tid + 512] = f2bf(av2 * s);
  if (tid == 0) {
    float c = 0.f;
    for (int w = 0; w < 16; ++w) c += keep[w];
    frac[b * LK_ + l] = c * s;
  }
}

// ---------------------------------------------------------------------------
// C = A @ B^T (+ epilogue).  128x128 tile, BK=32, 4 waves, 16x16x32 bf16 MFMA.
// MODE 0: out_bf16 = (acc + bias[c]) * scale               (Q projection)
// MODE 2: out_f32  = acc + bias[c]                         (output projection)
// MODE 3: acc + frac[r]*bias[c] -> Vf fragment-major       (V projection)
//         chunk (t,ct) is 16key x 16d = 256 elems:
//         idx = bh*16384 + (t*4+ct)*256 + hi*64 + fr*4 + jj
//         (t=key>>4, hi=(key>>2)&3, jj=key&3, ct=d>>4, fr=d&15)
// MODE 4: acc + frac[r]*bias[c] -> Kf fragment-major       (K projection)
//         chunk (t,kk) is 16key x 32d = 512 elems:
//         idx = bh*16384 + (t*2+kk)*512 + hi*128 + fr*8 + e
//         (t=key>>4, fr=key&15, kk=d>>5, hi=(d>>3)&3, e=d&7)
// ---------------------------------------------------------------------------
template<int AF32, int MODE>
__global__ __launch_bounds__(256) void gemm_bt(
    const void* __restrict__ Aptr, const float* __restrict__ Bw,
    const float* __restrict__ bias, const float* __restrict__ frac,
    void* __restrict__ Cout, int M, float scale)
{
  constexpr int K = DIM_;
  __shared__ unsigned short lA[128 * 32];
  __shared__ unsigned short lB[128 * 32];
  const int tid  = threadIdx.x;
  const int lane = tid & 63;
  const int wave = tid >> 6;
  const int brow = blockIdx.x * 128;
  const int bcol = blockIdx.y * 128;
  const int wr   = (wave >> 1) * 64;
  const int wc   = (wave & 1) * 64;
  const int fr   = lane & 15;
  const int fk   = (lane >> 4) * 8;

  f32x4 acc[4][4];
  #pragma unroll
  for (int i = 0; i < 4; ++i)
    #pragma unroll
    for (int j = 0; j < 4; ++j) acc[i][j] = (f32x4){0.f, 0.f, 0.f, 0.f};

  const int srow = tid >> 2;           // 0..63
  const int schk = (tid & 3) * 8;      // k element offset

  for (int k0 = 0; k0 < K; k0 += 32) {
    us8 a0, a1, b0, b1;
    if (AF32) {
      const float* A = (const float*)Aptr;
      a0 = cvt8(A + (size_t)(brow + srow) * K + k0 + schk);
      a1 = cvt8(A + (size_t)(brow + srow + 64) * K + k0 + schk);
    } else {
      const unsigned short* A = (const unsigned short*)Aptr;
      a0 = *(const us8*)(A + (size_t)(brow + srow) * K + k0 + schk);
      a1 = *(const us8*)(A + (size_t)(brow + srow + 64) * K + k0 + schk);
    }
    b0 = cvt8(Bw + (size_t)(bcol + srow) * K + k0 + schk);
    b1 = cvt8(Bw + (size_t)(bcol + srow + 64) * K + k0 + schk);
    __syncthreads();
    *(us8*)&lA[srow * 32 + schk]        = a0;
    *(us8*)&lA[(srow + 64) * 32 + schk] = a1;
    *(us8*)&lB[srow * 32 + schk]        = b0;
    *(us8*)&lB[(srow + 64) * 32 + schk] = b1;
    __syncthreads();
    bf8 af[4], bfv[4];
    #pragma unroll
    for (int mi = 0; mi < 4; ++mi)
      af[mi] = *(const bf8*)&lA[(wr + mi * 16 + fr) * 32 + fk];
    #pragma unroll
    for (int ni = 0; ni < 4; ++ni)
      bfv[ni] = *(const bf8*)&lB[(wc + ni * 16 + fr) * 32 + fk];
    #pragma unroll
    for (int mi = 0; mi < 4; ++mi)
      #pragma unroll
      for (int ni = 0; ni < 4; ++ni)
        acc[mi][ni] = __builtin_amdgcn_mfma_f32_16x16x32_bf16(af[mi], bfv[ni], acc[mi][ni], 0, 0, 0);
  }

  const int er = (lane >> 4) * 4;
  #pragma unroll
  for (int mi = 0; mi < 4; ++mi) {
    #pragma unroll
    for (int ni = 0; ni < 4; ++ni) {
      #pragma unroll
      for (int j = 0; j < 4; ++j) {
        const int r = brow + wr + mi * 16 + er + j;
        const int c = bcol + wc + ni * 16 + fr;
        float v = acc[mi][ni][j];
        if (MODE == 0) {
          v = (v + bias[c]) * scale;
          ((unsigned short*)Cout)[(size_t)r * DIM_ + c] = f2bf(v);
        } else if (MODE == 2) {
          ((float*)Cout)[(size_t)r * DIM_ + c] = v + bias[c];
        } else if (MODE == 3) {
          v += frac[r] * bias[c];
          const int bb = r >> 8, key = r & 255;
          const int hh = c >> 6, dd = c & 63;
          const int bh = bb * NH_ + hh;
          const size_t idx = (size_t)bh * 16384 +
              ((key >> 4) * 4 + (dd >> 4)) * 256 + ((key >> 2) & 3) * 64 +
              (dd & 15) * 4 + (key & 3);
          ((unsigned short*)Cout)[idx] = f2bf(v);
        } else {                       // MODE 4
          v += frac[r] * bias[c];
          const int bb = r >> 8, key = r & 255;
          const int hh = c >> 6, dd = c & 63;
          const int bh = bb * NH_ + hh;
          const size_t idx = (size_t)bh * 16384 +
              ((key >> 4) * 2 + (dd >> 5)) * 512 + ((dd >> 3) & 3) * 128 +
              (key & 15) * 8 + (dd & 7);
          ((unsigned short*)Cout)[idx] = f2bf(v);
        }
      }
    }
  }
}

// ---------------------------------------------------------------------------
// Fused low-rank attention — no LDS, no barriers.
// Block = one (b,h) x 128 q-rows, 4 waves x 32 rows (2 q-tiles per wave).
// K/V fragments stream straight from fragment-major Kf/Vf in global:
// every access is base + lane*width (perfectly coalesced, L2-resident,
// L1-shared across the block's 4 waves).  Swapped QK^T -> in-lane softmax
// + 2 shfl; P feeds K=16 PV MFMAs from registers.
// ---------------------------------------------------------------------------
__global__ __launch_bounds__(256, 3) void attn_fused(
    const unsigned short* __restrict__ Qh,   // [4,4096,768] bf16 (pre-scaled)
    const unsigned short* __restrict__ Kf,   // [48][16384] bf16 fragment-major
    const unsigned short* __restrict__ Vf,   // [48][16384] bf16 fragment-major
    unsigned short* __restrict__ ctx)        // [4,4096,768] bf16
{
  const int tid  = threadIdx.x;
  const int lane = tid & 63;
  const int wave = tid >> 6;
  const int bh = blockIdx.y;
  const int b = bh / NH_, h = bh % NH_;
  const int fr = lane & 15;
  const int hi = lane >> 4;

  // ---- Q fragments for both q-tiles
  const int qrow0 = blockIdx.x * 128 + wave * 32;
  const unsigned short* qp0 = Qh + (size_t)(b * SEQ_ + qrow0 + fr) * DIM_ + h * HD_ + hi * 8;
  const unsigned short* qp1 = qp0 + 16 * DIM_;
  const bf8 q00 = *(const bf8*)qp0;
  const bf8 q01 = *(const bf8*)(qp0 + 32);
  const bf8 q10 = *(const bf8*)qp1;
  const bf8 q11 = *(const bf8*)(qp1 + 32);

  // ---- QK^T for both tiles, each K fragment loaded once, shared
  const unsigned short* kb = Kf + (size_t)bh * 16384 + lane * 8;
  f32x4 sc0[16], sc1[16];
  #pragma unroll
  for (int t = 0; t < 16; ++t) {
    const bf8 kf0 = *(const bf8*)(kb + (t * 2 + 0) * 512);
    const bf8 kf1 = *(const bf8*)(kb + (t * 2 + 1) * 512);
    f32x4 a0 = (f32x4){0.f, 0.f, 0.f, 0.f};
    f32x4 a1 = (f32x4){0.f, 0.f, 0.f, 0.f};
    a0 = __builtin_amdgcn_mfma_f32_16x16x32_bf16(kf0, q00, a0, 0, 0, 0);
    a0 = __builtin_amdgcn_mfma_f32_16x16x32_bf16(kf1, q01, a0, 0, 0, 0);
    a1 = __builtin_amdgcn_mfma_f32_16x16x32_bf16(kf0, q10, a1, 0, 0, 0);
    a1 = __builtin_amdgcn_mfma_f32_16x16x32_bf16(kf1, q11, a1, 0, 0, 0);
    sc0[t] = a0; sc1[t] = a1;
  }

  // ---- softmax (per q-column fr): in-lane 64 values + shfl over hi groups
  bf4 pa0[16], pa1[16];
  {
    float m = -1e30f;
    #pragma unroll
    for (int t = 0; t < 16; ++t)
      #pragma unroll
      for (int j = 0; j < 4; ++j) m = fmaxf(m, sc0[t][j]);
    m = fmaxf(m, __shfl_xor(m, 16));
    m = fmaxf(m, __shfl_xor(m, 32));
    float s = 0.f;
    #pragma unroll
    for (int t = 0; t < 16; ++t)
      #pragma unroll
      for (int j = 0; j < 4; ++j) { float p = __expf(sc0[t][j] - m); sc0[t][j] = p; s += p; }
    s += __shfl_xor(s, 16);
    s += __shfl_xor(s, 32);
    const float inv = 1.f / s;
    #pragma unroll
    for (int t = 0; t < 16; ++t) {
      bf4 p;
      #pragma unroll
      for (int j = 0; j < 4; ++j) p[j] = (short)f2bf(sc0[t][j] * inv);
      pa0[t] = p;
    }
  }
  {
    float m = -1e30f;
    #pragma unroll
    for (int t = 0; t < 16; ++t)
      #pragma unroll
      for (int j = 0; j < 4; ++j) m = fmaxf(m, sc1[t][j]);
    m = fmaxf(m, __shfl_xor(m, 16));
    m = fmaxf(m, __shfl_xor(m, 32));
    float s = 0.f;
    #pragma unroll
    for (int t = 0; t < 16; ++t)
      #pragma unroll
      for (int j = 0; j < 4; ++j) { float p = __expf(sc1[t][j] - m); sc1[t][j] = p; s += p; }
    s += __shfl_xor(s, 16);
    s += __shfl_xor(s, 32);
    const float inv = 1.f / s;
    #pragma unroll
    for (int t = 0; t < 16; ++t) {
      bf4 p;
      #pragma unroll
      for (int j = 0; j < 4; ++j) p[j] = (short)f2bf(sc1[t][j] * inv);
      pa1[t] = p;
    }
  }

  // ---- PV: each V fragment loaded once, shared by both tiles
  const unsigned short* vb = Vf + (size_t)bh * 16384 + lane * 4;
  f32x4 acc0[4], acc1[4];
  #pragma unroll
  for (int ct = 0; ct < 4; ++ct) {
    acc0[ct] = (f32x4){0.f, 0.f, 0.f, 0.f};
    acc1[ct] = (f32x4){0.f, 0.f, 0.f, 0.f};
  }
  #pragma unroll
  for (int t = 0; t < 16; ++t) {
    #pragma unroll
    for (int ct = 0; ct < 4; ++ct) {
      const bf4 vf = *(const bf4*)(vb + (t * 4 + ct) * 256);
      acc0[ct] = mfma16bf16(pa0[t], vf, acc0[ct]);
      acc1[ct] = mfma16bf16(pa1[t], vf, acc1[ct]);
    }
  }

  // ---- ctx writes: lane holds ctx[q=qrow+hi*4+j][d=h*64+ct*16+fr]
  #pragma unroll
  for (int ct = 0; ct < 4; ++ct)
    #pragma unroll
    for (int j = 0; j < 4; ++j) {
      ctx[(size_t)(b * SEQ_ + qrow0 + hi * 4 + j) * DIM_ + h * HD_ + ct * 16 + fr] =
          f2bf(acc0[ct][j]);
      ctx[(size_t)(b * SEQ_ + qrow0 + 16 + hi * 4 + j) * DIM_ + h * HD_ + ct * 16 + fr] =
          f2bf(acc1[ct][j]);
    }
}

// ---------------------------------------------------------------------------
extern "C" void kernel_launch(void* const* d_in, const int* in_sizes, int n_in,
                              void* d_out, int out_size, void* d_ws, size_t ws_size,
                              hipStream_t stream) {
  const float* query = (const float*)d_in[0];
  const float* key   = (const float*)d_in[1];
  const float* value = (const float*)d_in[2];
  const float* mask  = (const float*)d_in[3];
  const float* Wq    = (const float*)d_in[4];
  const float* bq    = (const float*)d_in[5];
  const float* Wk    = (const float*)d_in[6];
  const float* bk    = (const float*)d_in[7];
  const float* Wv    = (const float*)d_in[8];
  const float* bv    = (const float*)d_in[9];
  const float* Wo    = (const float*)d_in[10];
  const float* bo    = (const float*)d_in[11];
  float* out = (float*)d_out;

  char* ws = (char*)d_ws;
  unsigned short* Qh  = (unsigned short*)ws;                  // 25,165,824 B
  unsigned short* ctx = (unsigned short*)(ws + 25165824);     // 25,165,824 B
  unsigned short* pK  = (unsigned short*)(ws + 50331648);     //  1,572,864 B
  unsigned short* pV  = (unsigned short*)(ws + 51904512);     //  1,572,864 B
  unsigned short* Kf  = (unsigned short*)(ws + 53477376);     //  1,572,864 B
  unsigned short* Vf  = (unsigned short*)(ws + 55050240);     //  1,572,864 B
  float*          frac = (float*)(ws + 56623104);             //      4,096 B

  pool_kernel<<<dim3(1024), dim3(256), 0, stream>>>(key, value, mask, pK, pV, frac);
  gemm_bt<1, 0><<<dim3(128, 6), dim3(256), 0, stream>>>(query, Wq, bq, nullptr, Qh, 16384, 0.125f);
  gemm_bt<0, 4><<<dim3(8, 6), dim3(256), 0, stream>>>(pK, Wk, bk, frac, Kf, 1024, 1.f);
  gemm_bt<0, 3><<<dim3(8, 6), dim3(256), 0, stream>>>(pV, Wv, bv, frac, Vf, 1024, 1.f);
  attn_fused<<<dim3(32, 48), dim3(256), 0, stream>>>(Qh, Kf, Vf, ctx);
  gemm_bt<0, 2><<<dim3(128, 6), dim3(256), 0, stream>>>(ctx, Wo, bo, nullptr, out, 16384, 1.f);
}

// Round 6
// 155.372 us; speedup vs baseline: 1.2485x; 1.2485x over previous
//
#include <hip/hip_runtime.h>

#define BS_   4
#define SEQ_  4096
#define DIM_  768
#define NH_   12
#define HD_   64
#define LK_   256

typedef __attribute__((ext_vector_type(8))) short          bf8;
typedef __attribute__((ext_vector_type(8))) unsigned short us8;
typedef __attribute__((ext_vector_type(4))) float          f32x4;

typedef unsigned int u32g __attribute__((address_space(1)));
typedef unsigned int u32l __attribute__((address_space(3)));

#define LOG2E 1.44269504088896340736f

__device__ __forceinline__ unsigned short f2bf(float f) {
  unsigned u = __builtin_bit_cast(unsigned, f);
  u += 0x7fffu + ((u >> 16) & 1u);   // round-to-nearest-even
  return (unsigned short)(u >> 16);
}

__device__ __forceinline__ us8 cvt8(const float* __restrict__ p) {
  const float4 a = *(const float4*)p;
  const float4 b = *(const float4*)(p + 4);
  us8 r;
  r[0] = f2bf(a.x); r[1] = f2bf(a.y); r[2] = f2bf(a.z); r[3] = f2bf(a.w);
  r[4] = f2bf(b.x); r[5] = f2bf(b.y); r[6] = f2bf(b.z); r[7] = f2bf(b.w);
  return r;
}

// ---------------------------------------------------------------------------
// bf16 pre-conversion: query (12.58M) + the four 768x768 weights.
// ---------------------------------------------------------------------------
__global__ __launch_bounds__(256) void cvtbf_kernel(
    const float* __restrict__ query,
    const float* __restrict__ Wq, const float* __restrict__ Wk,
    const float* __restrict__ Wv, const float* __restrict__ Wo,
    unsigned short* __restrict__ Qbf, unsigned short* __restrict__ Wbf)
{
  const int i = blockIdx.x * 256 + threadIdx.x;   // us8 index
  const int QN8 = (BS_ * SEQ_ * DIM_) / 8;        // 1572864
  const int WN8 = (DIM_ * DIM_) / 8;              // 73728
  if (i < QN8) { *(us8*)(Qbf + (size_t)i * 8) = cvt8(query + (size_t)i * 8); return; }
  int j = i - QN8;
  const float* src; unsigned short* dst;
  if      (j <     WN8) { src = Wq; dst = Wbf;                   }
  else if (j < 2 * WN8) { src = Wk; dst = Wbf + DIM_*DIM_;     j -=     WN8; }
  else if (j < 3 * WN8) { src = Wv; dst = Wbf + 2*DIM_*DIM_;   j -= 2 * WN8; }
  else if (j < 4 * WN8) { src = Wo; dst = Wbf + 3*DIM_*DIM_;   j -= 3 * WN8; }
  else return;
  *(us8*)(dst + (size_t)j * 8) = cvt8(src + (size_t)j * 8);
}

// ---------------------------------------------------------------------------
// Pool: pooled[b,l,d] = (1/16) sum_w keep(b,l*16+w) * x[b,l*16+w,d]  (bf16 out)
// ---------------------------------------------------------------------------
__global__ __launch_bounds__(256) void pool_kernel(
    const float* __restrict__ key, const float* __restrict__ value,
    const float* __restrict__ mask,
    unsigned short* __restrict__ pk, unsigned short* __restrict__ pv,
    float* __restrict__ frac)
{
  const int blk = blockIdx.x;          // 0..1023
  const int b = blk >> 8;
  const int l = blk & 255;
  const int tid = threadIdx.x;
  __shared__ float keep[16];
  if (tid < 16) keep[tid] = (mask[b * SEQ_ + l * 16 + tid] >= 0.f) ? 1.f : 0.f;
  __syncthreads();
  float ak0 = 0.f, ak1 = 0.f, ak2 = 0.f, av0 = 0.f, av1 = 0.f, av2 = 0.f;
  #pragma unroll 1
  for (int w = 0; w < 16; ++w) {
    if (keep[w] != 0.f) {              // block-uniform branch
      const size_t row = (size_t)(b * SEQ_ + l * 16 + w) * DIM_;
      const float* kr = key + row;
      const float* vr = value + row;
      ak0 += kr[tid]; ak1 += kr[tid + 256]; ak2 += kr[tid + 512];
      av0 += vr[tid]; av1 += vr[tid + 256]; av2 += vr[tid + 512];
    }
  }
  const size_t o = (size_t)(b * LK_ + l) * DIM_;
  const float s = 1.f / 16.f;
  pk[o + tid] = f2bf(ak0 * s); pk[o + tid + 256] = f2bf(ak1 * s); pk[o + tid + 512] = f2bf(ak2 * s);
  pv[o + tid] = f2bf(av0 * s); pv[o + tid + 256] = f2bf(av1 * s); pv[o + tid + 512] = f2bf(av2 * s);
  if (tid == 0) {
    float c = 0.f;
    for (int w = 0; w < 16; ++w) c += keep[w];
    frac[b * LK_ + l] = c * s;
  }
}

// ---------------------------------------------------------------------------
// C = A @ B^T (+ epilogue).  128x128 tile, BK=32, 4 waves, 16x16x32 bf16 MFMA.
// SA/SB: 0 = bf16 source staged via global_load_lds (lane-linear LDS),
//        1 = f32 source converted in-register then ds_write.
// MODE 0: out_bf16 = (acc + bias[c]) * scale               (Q projection)
// MODE 2: out_f32  = acc + bias[c]                         (output projection)
// MODE 3: acc + frac[r]*bias[c] -> Vf, K=32 B-frag order   (V projection)
//         idx = bh*16384 + (s*4+ct)*512 + hi*128 + fr*8 + e
//         (s=key>>5, hi=(key>>3)&3, e=key&7, ct=d>>4, fr=d&15)
// MODE 4: acc + frac[r]*bias[c] -> Kf, key-rows PERMUTED so the two swapped
//         QK^T sub-tiles directly yield the K=32 PV A-fragment:
//         sub-tile rows r=g*4+j map to key = 32t + g*8 + sub*4 + j.
//         idx = bh*16384 + ((t*2+sub)*2+kk)*512 + hi*128 + fr_k*8 + e
//         (t=key>>5; g=(key>>3)&3; sub=(key>>2)&1; j=key&3; fr_k=g*4+j;
//          kk=d>>5; hi=(d>>3)&3; e=d&7)
// ---------------------------------------------------------------------------
template<int SA, int SB, int MODE>
__global__ __launch_bounds__(256) void gemm_bt(
    const void* __restrict__ Aptr, const void* __restrict__ Bptr,
    const float* __restrict__ bias, const float* __restrict__ frac,
    void* __restrict__ Cout, int M, float scale)
{
  constexpr int K = DIM_;
  __shared__ __align__(16) unsigned short lA[128 * 32];
  __shared__ __align__(16) unsigned short lB[128 * 32];
  const int tid  = threadIdx.x;
  const int lane = tid & 63;
  const int wave = tid >> 6;
  const int brow = blockIdx.x * 128;
  const int bcol = blockIdx.y * 128;
  const int wr   = (wave >> 1) * 64;
  const int wc   = (wave & 1) * 64;
  const int fr   = lane & 15;
  const int fk   = (lane >> 4) * 8;

  f32x4 acc[4][4];
  #pragma unroll
  for (int i = 0; i < 4; ++i)
    #pragma unroll
    for (int j = 0; j < 4; ++j) acc[i][j] = (f32x4){0.f, 0.f, 0.f, 0.f};

  const int srow = tid >> 2;           // 0..63
  const int schk = (tid & 3) * 8;      // k element offset

  for (int k0 = 0; k0 < K; k0 += 32) {
    us8 a0, a1, b0, b1;
    if (SA == 1) {
      const float* A = (const float*)Aptr;
      a0 = cvt8(A + (size_t)(brow + srow) * K + k0 + schk);
      a1 = cvt8(A + (size_t)(brow + srow + 64) * K + k0 + schk);
    }
    if (SB == 1) {
      const float* B = (const float*)Bptr;
      b0 = cvt8(B + (size_t)(bcol + srow) * K + k0 + schk);
      b1 = cvt8(B + (size_t)(bcol + srow + 64) * K + k0 + schk);
    }
    __syncthreads();                   // prior reads done before overwrite
    if (SA == 0) {
      const unsigned short* A = (const unsigned short*)Aptr;
      __builtin_amdgcn_global_load_lds(
          (const u32g*)(A + (size_t)(brow + srow) * K + k0 + schk),
          (u32l*)&lA[tid * 8], 16, 0, 0);
      __builtin_amdgcn_global_load_lds(
          (const u32g*)(A + (size_t)(brow + srow + 64) * K + k0 + schk),
          (u32l*)&lA[2048 + tid * 8], 16, 0, 0);
    } else {
      *(us8*)&lA[tid * 8]        = a0;
      *(us8*)&lA[2048 + tid * 8] = a1;
    }
    if (SB == 0) {
      const unsigned short* B = (const unsigned short*)Bptr;
      __builtin_amdgcn_global_load_lds(
          (const u32g*)(B + (size_t)(bcol + srow) * K + k0 + schk),
          (u32l*)&lB[tid * 8], 16, 0, 0);
      __builtin_amdgcn_global_load_lds(
          (const u32g*)(B + (size_t)(bcol + srow + 64) * K + k0 + schk),
          (u32l*)&lB[2048 + tid * 8], 16, 0, 0);
    } else {
      *(us8*)&lB[tid * 8]        = b0;
      *(us8*)&lB[2048 + tid * 8] = b1;
    }
    __syncthreads();                   // drains DMA vmcnt + ds_writes
    bf8 af[4], bfv[4];
    #pragma unroll
    for (int mi = 0; mi < 4; ++mi)
      af[mi] = *(const bf8*)&lA[(wr + mi * 16 + fr) * 32 + fk];
    #pragma unroll
    for (int ni = 0; ni < 4; ++ni)
      bfv[ni] = *(const bf8*)&lB[(wc + ni * 16 + fr) * 32 + fk];
    #pragma unroll
    for (int mi = 0; mi < 4; ++mi)
      #pragma unroll
      for (int ni = 0; ni < 4; ++ni)
        acc[mi][ni] = __builtin_amdgcn_mfma_f32_16x16x32_bf16(af[mi], bfv[ni], acc[mi][ni], 0, 0, 0);
  }

  const int er = (lane >> 4) * 4;
  #pragma unroll
  for (int mi = 0; mi < 4; ++mi) {
    #pragma unroll
    for (int ni = 0; ni < 4; ++ni) {
      #pragma unroll
      for (int j = 0; j < 4; ++j) {
        const int r = brow + wr + mi * 16 + er + j;
        const int c = bcol + wc + ni * 16 + fr;
        float v = acc[mi][ni][j];
        if (MODE == 0) {
          v = (v + bias[c]) * scale;
          ((unsigned short*)Cout)[(size_t)r * DIM_ + c] = f2bf(v);
        } else if (MODE == 2) {
          ((float*)Cout)[(size_t)r * DIM_ + c] = v + bias[c];
        } else if (MODE == 3) {
          v += frac[r] * bias[c];
          const int bb = r >> 8, key = r & 255;
          const int hh = c >> 6, dd = c & 63;
          const int bh = bb * NH_ + hh;
          const size_t idx = (size_t)bh * 16384 +
              ((key >> 5) * 4 + (dd >> 4)) * 512 + ((key >> 3) & 3) * 128 +
              (dd & 15) * 8 + (key & 7);
          ((unsigned short*)Cout)[idx] = f2bf(v);
        } else {                       // MODE 4: permuted-key K fragments
          v += frac[r] * bias[c];
          const int bb = r >> 8, key = r & 255;
          const int hh = c >> 6, dd = c & 63;
          const int bh = bb * NH_ + hh;
          const int t = key >> 5, g = (key >> 3) & 3, sub = (key >> 2) & 1, jj = key & 3;
          const int frk = g * 4 + jj;
          const size_t idx = (size_t)bh * 16384 +
              (((t * 2 + sub) * 2) + (dd >> 5)) * 512 + ((dd >> 3) & 3) * 128 +
              frk * 8 + (dd & 7);
          ((unsigned short*)Cout)[idx] = f2bf(v);
        }
      }
    }
  }
}

// ---------------------------------------------------------------------------
// Fused low-rank attention — no LDS, no barriers, all 16x16x32 MFMA.
// Wave = 16 q-rows; block = 4 waves = 64 rows; grid 64 x 48.
// Swapped QK^T with PERMUTED key-rows (MODE 4 layout): the two sub-tile
// C-fragments concatenate in-lane into the exact K=32 PV A-fragment.
// Scores are in log2 domain (Qh pre-scaled by 1/8*log2e) -> exp2f.
// ---------------------------------------------------------------------------
__global__ __launch_bounds__(256) void attn_fused(
    const unsigned short* __restrict__ Qh,   // [4,4096,768] bf16 (pre-scaled)
    const unsigned short* __restrict__ Kf,   // [48][16384] bf16 fragment-major
    const unsigned short* __restrict__ Vf,   // [48][16384] bf16 fragment-major
    unsigned short* __restrict__ ctx)        // [4,4096,768] bf16
{
  const int tid  = threadIdx.x;
  const int lane = tid & 63;
  const int wave = tid >> 6;
  const int bh = blockIdx.y;
  const int b = bh / NH_, h = bh % NH_;
  const int fr = lane & 15;
  const int hi = lane >> 4;
  const int qrow = blockIdx.x * 64 + wave * 16;

  const unsigned short* qp = Qh + (size_t)(b * SEQ_ + qrow + fr) * DIM_ + h * HD_ + hi * 8;
  const bf8 q0 = *(const bf8*)qp;
  const bf8 q1 = *(const bf8*)(qp + 32);

  // ---- QK^T: 8 key-groups of 32; chunks (s*4 + {0,1,2,3}) = {A:kk0,kk1, B:kk0,kk1}
  const unsigned short* kb = Kf + (size_t)bh * 16384 + lane * 8;
  f32x4 scA[8], scB[8];
  #pragma unroll
  for (int s = 0; s < 8; ++s) {
    const bf8 ka0 = *(const bf8*)(kb + (s * 4 + 0) * 512);
    const bf8 ka1 = *(const bf8*)(kb + (s * 4 + 1) * 512);
    const bf8 kb0 = *(const bf8*)(kb + (s * 4 + 2) * 512);
    const bf8 kb1 = *(const bf8*)(kb + (s * 4 + 3) * 512);
    f32x4 x = (f32x4){0.f, 0.f, 0.f, 0.f};
    x = __builtin_amdgcn_mfma_f32_16x16x32_bf16(ka0, q0, x, 0, 0, 0);
    x = __builtin_amdgcn_mfma_f32_16x16x32_bf16(ka1, q1, x, 0, 0, 0);
    scA[s] = x;
    f32x4 y = (f32x4){0.f, 0.f, 0.f, 0.f};
    y = __builtin_amdgcn_mfma_f32_16x16x32_bf16(kb0, q0, y, 0, 0, 0);
    y = __builtin_amdgcn_mfma_f32_16x16x32_bf16(kb1, q1, y, 0, 0, 0);
    scB[s] = y;
  }

  // ---- softmax over 256 keys of q-column fr (log2 domain)
  float m = -1e30f;
  #pragma unroll
  for (int s = 0; s < 8; ++s)
    #pragma unroll
    for (int j = 0; j < 4; ++j) { m = fmaxf(m, scA[s][j]); m = fmaxf(m, scB[s][j]); }
  m = fmaxf(m, __shfl_xor(m, 16));
  m = fmaxf(m, __shfl_xor(m, 32));
  float sum = 0.f;
  #pragma unroll
  for (int s = 0; s < 8; ++s)
    #pragma unroll
    for (int j = 0; j < 4; ++j) {
      float pa = exp2f(scA[s][j] - m); scA[s][j] = pa; sum += pa;
      float pb = exp2f(scB[s][j] - m); scB[s][j] = pb; sum += pb;
    }
  sum += __shfl_xor(sum, 16);
  sum += __shfl_xor(sum, 32);
  const float inv = 1.f / sum;

  // ---- pack P into K=32 A-fragments: e<4 from scA, e>=4 from scB
  bf8 pa[8];
  #pragma unroll
  for (int s = 0; s < 8; ++s) {
    bf8 p;
    #pragma unroll
    for (int j = 0; j < 4; ++j) {
      p[j]     = (short)f2bf(scA[s][j] * inv);
      p[4 + j] = (short)f2bf(scB[s][j] * inv);
    }
    pa[s] = p;
  }

  // ---- PV: K=256 as 8 K=32 steps, 4 d-tiles
  const unsigned short* vb = Vf + (size_t)bh * 16384 + lane * 8;
  f32x4 acc[4];
  #pragma unroll
  for (int ct = 0; ct < 4; ++ct) acc[ct] = (f32x4){0.f, 0.f, 0.f, 0.f};
  #pragma unroll
  for (int s = 0; s < 8; ++s) {
    #pragma unroll
    for (int ct = 0; ct < 4; ++ct) {
      const bf8 vf = *(const bf8*)(vb + (s * 4 + ct) * 512);
      acc[ct] = __builtin_amdgcn_mfma_f32_16x16x32_bf16(pa[s], vf, acc[ct], 0, 0, 0);
    }
  }

  // ---- ctx write: lane holds O[q=qrow+hi*4+j][d=h*64+ct*16+fr]
  #pragma unroll
  for (int ct = 0; ct < 4; ++ct)
    #pragma unroll
    for (int j = 0; j < 4; ++j)
      ctx[(size_t)(b * SEQ_ + qrow + hi * 4 + j) * DIM_ + h * HD_ + ct * 16 + fr] =
          f2bf(acc[ct][j]);
}

// ---------------------------------------------------------------------------
extern "C" void kernel_launch(void* const* d_in, const int* in_sizes, int n_in,
                              void* d_out, int out_size, void* d_ws, size_t ws_size,
                              hipStream_t stream) {
  const float* query = (const float*)d_in[0];
  const float* key   = (const float*)d_in[1];
  const float* value = (const float*)d_in[2];
  const float* mask  = (const float*)d_in[3];
  const float* Wq    = (const float*)d_in[4];
  const float* bq    = (const float*)d_in[5];
  const float* Wk    = (const float*)d_in[6];
  const float* bk    = (const float*)d_in[7];
  const float* Wv    = (const float*)d_in[8];
  const float* bv    = (const float*)d_in[9];
  const float* Wo    = (const float*)d_in[10];
  const float* bo    = (const float*)d_in[11];
  float* out = (float*)d_out;

  char* ws = (char*)d_ws;
  unsigned short* Qh  = (unsigned short*)ws;                  // 25,165,824 B
  unsigned short* ctx = (unsigned short*)(ws + 25165824);     // 25,165,824 B
  unsigned short* pK  = (unsigned short*)(ws + 50331648);     //  1,572,864 B
  unsigned short* pV  = (unsigned short*)(ws + 51904512);     //  1,572,864 B
  unsigned short* Kf  = (unsigned short*)(ws + 53477376);     //  1,572,864 B
  unsigned short* Vf  = (unsigned short*)(ws + 55050240);     //  1,572,864 B
  float*          frac = (float*)(ws + 56623104);             //      4,096 B
  unsigned short* Wbf = (unsigned short*)(ws + 56627200);     //  4,718,592 B (optional)
  const size_t NEED_BF = 56627200 + 4718592;

  const float qscale = 0.125f * LOG2E;   // 1/sqrt(64) and e->2 exponent base

  pool_kernel<<<dim3(1024), dim3(256), 0, stream>>>(key, value, mask, pK, pV, frac);

  if (ws_size >= NEED_BF) {
    // full-bf16 path: pre-convert query (into ctx alias, dead until attn) + weights
    unsigned short* Qbf = ctx;
    cvtbf_kernel<<<dim3(7296), dim3(256), 0, stream>>>(query, Wq, Wk, Wv, Wo, Qbf, Wbf);
    gemm_bt<0, 0, 0><<<dim3(128, 6), dim3(256), 0, stream>>>(Qbf, Wbf,                 bq, nullptr, Qh, 16384, qscale);
    gemm_bt<0, 0, 4><<<dim3(8, 6),   dim3(256), 0, stream>>>(pK,  Wbf + DIM_*DIM_,     bk, frac,    Kf, 1024, 1.f);
    gemm_bt<0, 0, 3><<<dim3(8, 6),   dim3(256), 0, stream>>>(pV,  Wbf + 2*DIM_*DIM_,   bv, frac,    Vf, 1024, 1.f);
    attn_fused<<<dim3(64, 48), dim3(256), 0, stream>>>(Qh, Kf, Vf, ctx);
    gemm_bt<0, 0, 2><<<dim3(128, 6), dim3(256), 0, stream>>>(ctx, Wbf + 3*DIM_*DIM_,   bo, nullptr, out, 16384, 1.f);
  } else {
    // fallback: f32 sources converted in the stager
    gemm_bt<1, 1, 0><<<dim3(128, 6), dim3(256), 0, stream>>>(query, Wq, bq, nullptr, Qh, 16384, qscale);
    gemm_bt<0, 1, 4><<<dim3(8, 6),   dim3(256), 0, stream>>>(pK,    Wk, bk, frac,    Kf, 1024, 1.f);
    gemm_bt<0, 1, 3><<<dim3(8, 6),   dim3(256), 0, stream>>>(pV,    Wv, bv, frac,    Vf, 1024, 1.f);
    attn_fused<<<dim3(64, 48), dim3(256), 0, stream>>>(Qh, Kf, Vf, ctx);
    gemm_bt<0, 1, 2><<<dim3(128, 6), dim3(256), 0, stream>>>(ctx,   Wo, bo, nullptr, out, 16384, 1.f);
  }
}

// Round 9
// 140.339 us; speedup vs baseline: 1.3822x; 1.1071x over previous
//
#include <hip/hip_runtime.h>

#define BS_   4
#define SEQ_  4096
#define DIM_  768
#define NH_   12
#define HD_   64
#define LK_   256

typedef __attribute__((ext_vector_type(8))) short          bf8;
typedef __attribute__((ext_vector_type(8))) unsigned short us8;
typedef __attribute__((ext_vector_type(4))) unsigned short us4;
typedef __attribute__((ext_vector_type(4))) float          f32x4;

typedef unsigned int u32g __attribute__((address_space(1)));
typedef unsigned int u32l __attribute__((address_space(3)));

#define LOG2E 1.44269504088896340736f

__device__ __forceinline__ unsigned short f2bf(float f) {
  unsigned u = __builtin_bit_cast(unsigned, f);
  u += 0x7fffu + ((u >> 16) & 1u);   // round-to-nearest-even
  return (unsigned short)(u >> 16);
}

__device__ __forceinline__ us8 cvt8(const float* __restrict__ p) {
  const float4 a = *(const float4*)p;
  const float4 b = *(const float4*)(p + 4);
  us8 r;
  r[0] = f2bf(a.x); r[1] = f2bf(a.y); r[2] = f2bf(a.z); r[3] = f2bf(a.w);
  r[4] = f2bf(b.x); r[5] = f2bf(b.y); r[6] = f2bf(b.z); r[7] = f2bf(b.w);
  return r;
}

// ---------------------------------------------------------------------------
// bf16 pre-conversion: query (12.58M) + the four 768x768 weights.
// ---------------------------------------------------------------------------
__global__ __launch_bounds__(256) void cvtbf_kernel(
    const float* __restrict__ query,
    const float* __restrict__ Wq, const float* __restrict__ Wk,
    const float* __restrict__ Wv, const float* __restrict__ Wo,
    unsigned short* __restrict__ Qbf, unsigned short* __restrict__ Wbf)
{
  const int i = blockIdx.x * 256 + threadIdx.x;   // us8 index
  const int QN8 = (BS_ * SEQ_ * DIM_) / 8;        // 1572864
  const int WN8 = (DIM_ * DIM_) / 8;              // 73728
  if (i < QN8) { *(us8*)(Qbf + (size_t)i * 8) = cvt8(query + (size_t)i * 8); return; }
  int j = i - QN8;
  const float* src; unsigned short* dst;
  if      (j <     WN8) { src = Wq; dst = Wbf;                   }
  else if (j < 2 * WN8) { src = Wk; dst = Wbf + DIM_*DIM_;     j -=     WN8; }
  else if (j < 3 * WN8) { src = Wv; dst = Wbf + 2*DIM_*DIM_;   j -= 2 * WN8; }
  else if (j < 4 * WN8) { src = Wo; dst = Wbf + 3*DIM_*DIM_;   j -= 3 * WN8; }
  else return;
  *(us8*)(dst + (size_t)j * 8) = cvt8(src + (size_t)j * 8);
}

// ---------------------------------------------------------------------------
// Pool (float4-vectorized): 384 threads; lanes 0-191 pool key, 192-383 value.
// pooled[b,l,d] = (1/16) sum_w keep * x[b,l*16+w,d]; frac = kept/16.
// ---------------------------------------------------------------------------
__global__ __launch_bounds__(384) void pool_kernel(
    const float* __restrict__ key, const float* __restrict__ value,
    const float* __restrict__ mask,
    unsigned short* __restrict__ pk, unsigned short* __restrict__ pv,
    float* __restrict__ frac)
{
  const int blk = blockIdx.x;          // 0..1023
  const int b = blk >> 8;
  const int l = blk & 255;
  const int tid = threadIdx.x;
  __shared__ float keep[16];
  if (tid < 16) keep[tid] = (mask[b * SEQ_ + l * 16 + tid] >= 0.f) ? 1.f : 0.f;
  __syncthreads();
  const int isV = tid >= 192;
  const int c = isV ? tid - 192 : tid;            // float4 chunk 0..191
  const float* src = isV ? value : key;
  float4 acc = make_float4(0.f, 0.f, 0.f, 0.f);
  #pragma unroll 1
  for (int w = 0; w < 16; ++w) {
    if (keep[w] != 0.f) {
      const float4 v = *(const float4*)(src + (size_t)(b * SEQ_ + l * 16 + w) * DIM_ + c * 4);
      acc.x += v.x; acc.y += v.y; acc.z += v.z; acc.w += v.w;
    }
  }
  const float s = 1.f / 16.f;
  unsigned short* dst = isV ? pv : pk;
  us4 o4;
  o4[0] = f2bf(acc.x * s); o4[1] = f2bf(acc.y * s);
  o4[2] = f2bf(acc.z * s); o4[3] = f2bf(acc.w * s);
  *(us4*)(dst + (size_t)(b * LK_ + l) * DIM_ + c * 4) = o4;
  if (tid == 0) {
    float cnt = 0.f;
    for (int w = 0; w < 16; ++w) cnt += keep[w];
    frac[b * LK_ + l] = cnt * s;
  }
}

// ---------------------------------------------------------------------------
// C = A @ B^T (+ epilogue), bf16 inputs staged via global_load_lds.
// 128x128 tile, BK=32, 4 waves, 16x16x32 bf16 MFMA.
// SWZ: 1D grid of 768, XCD-chunked swizzle (8 XCDs x 96 blocks; 16 A-panels
//      x 6 col-blocks contiguous per XCD for L2 A-panel reuse).
// MODE 0: out_bf16 = (acc + bias[c]) * scale               (Q projection)
// MODE 2: out_f32  = acc + bias[c]                         (output projection)
// MODE 34: fused K/V projection pair, blockIdx.z selects:
//   z=0 (K): acc + frac[r]*bias[c] -> Kf, key-rows permuted so the two
//            swapped-QK^T sub-tiles concatenate into the K=32 PV A-fragment:
//            t=key>>5; g=(key>>3)&3; sub=(key>>2)&1; j=key&3; frk=g*4+j;
//            idx = bh*16384 + ((t*2+sub)*2+(d>>5))*512 + ((d>>3)&3)*128
//                  + frk*8 + (d&7)
//   z=1 (V): acc + frac[r]*bias2[c] -> Vf, K=32 B-frag order:
//            idx = bh*16384 + ((key>>5)*4+(d>>4))*512 + ((key>>3)&3)*128
//                  + (d&15)*8 + (key&7)   (+786432 elems for the V region)
// ---------------------------------------------------------------------------
template<int MODE, int SWZ>
__global__ __launch_bounds__(256) void gemm_bt(
    const void* __restrict__ Aptr_, const void* __restrict__ Bptr_,
    const float* __restrict__ bias, const float* __restrict__ bias2,
    const float* __restrict__ frac,
    void* __restrict__ Cout, float scale)
{
  constexpr int K = DIM_;
  __shared__ __align__(16) unsigned short lA[128 * 32];
  __shared__ __align__(16) unsigned short lB[128 * 32];
  const int tid  = threadIdx.x;
  const int lane = tid & 63;
  const int wave = tid >> 6;

  int bx, by;
  if (SWZ) {
    const int r = (blockIdx.x & 7) * 96 + (blockIdx.x >> 3);
    bx = r / 6; by = r % 6;
  } else {
    bx = blockIdx.x; by = blockIdx.y;
  }
  const int brow = bx * 128;
  const int bcol = by * 128;

  const unsigned short* A = (const unsigned short*)Aptr_;
  const unsigned short* Bw = (const unsigned short*)Bptr_;
  const float* bb = bias;
  int isV = 0;
  if (MODE == 34) {
    isV = blockIdx.z;
    A  += (size_t)isV * (BS_ * LK_ * DIM_);    // pV follows pK
    Bw += (size_t)isV * (DIM_ * DIM_);         // Wv follows Wk
    if (isV) bb = bias2;
  }

  const int wr   = (wave >> 1) * 64;
  const int wc   = (wave & 1) * 64;
  const int fr   = lane & 15;
  const int fk   = (lane >> 4) * 8;

  f32x4 acc[4][4];
  #pragma unroll
  for (int i = 0; i < 4; ++i)
    #pragma unroll
    for (int j = 0; j < 4; ++j) acc[i][j] = (f32x4){0.f, 0.f, 0.f, 0.f};

  const int srow = tid >> 2;           // 0..63
  const int schk = (tid & 3) * 8;      // k element offset

  for (int k0 = 0; k0 < K; k0 += 32) {
    __syncthreads();                   // prior reads done before overwrite
    __builtin_amdgcn_global_load_lds(
        (const u32g*)(A + (size_t)(brow + srow) * K + k0 + schk),
        (u32l*)&lA[tid * 8], 16, 0, 0);
    __builtin_amdgcn_global_load_lds(
        (const u32g*)(A + (size_t)(brow + srow + 64) * K + k0 + schk),
        (u32l*)&lA[2048 + tid * 8], 16, 0, 0);
    __builtin_amdgcn_global_load_lds(
        (const u32g*)(Bw + (size_t)(bcol + srow) * K + k0 + schk),
        (u32l*)&lB[tid * 8], 16, 0, 0);
    __builtin_amdgcn_global_load_lds(
        (const u32g*)(Bw + (size_t)(bcol + srow + 64) * K + k0 + schk),
        (u32l*)&lB[2048 + tid * 8], 16, 0, 0);
    __syncthreads();                   // drains DMA vmcnt
    bf8 af[4], bfv[4];
    #pragma unroll
    for (int mi = 0; mi < 4; ++mi)
      af[mi] = *(const bf8*)&lA[(wr + mi * 16 + fr) * 32 + fk];
    #pragma unroll
    for (int ni = 0; ni < 4; ++ni)
      bfv[ni] = *(const bf8*)&lB[(wc + ni * 16 + fr) * 32 + fk];
    #pragma unroll
    for (int mi = 0; mi < 4; ++mi)
      #pragma unroll
      for (int ni = 0; ni < 4; ++ni)
        acc[mi][ni] = __builtin_amdgcn_mfma_f32_16x16x32_bf16(af[mi], bfv[ni], acc[mi][ni], 0, 0, 0);
  }

  const int er = (lane >> 4) * 4;
  #pragma unroll
  for (int mi = 0; mi < 4; ++mi) {
    #pragma unroll
    for (int ni = 0; ni < 4; ++ni) {
      #pragma unroll
      for (int j = 0; j < 4; ++j) {
        const int r = brow + wr + mi * 16 + er + j;
        const int c = bcol + wc + ni * 16 + fr;
        float v = acc[mi][ni][j];
        if (MODE == 0) {
          v = (v + bias[c]) * scale;
          ((unsigned short*)Cout)[(size_t)r * DIM_ + c] = f2bf(v);
        } else if (MODE == 2) {
          ((float*)Cout)[(size_t)r * DIM_ + c] = v + bias[c];
        } else {                       // MODE 34
          v += frac[r] * bb[c];
          const int bb_ = r >> 8, key = r & 255;
          const int hh = c >> 6, dd = c & 63;
          const int bh = bb_ * NH_ + hh;
          size_t idx;
          if (isV) {
            idx = (size_t)bh * 16384 +
                ((key >> 5) * 4 + (dd >> 4)) * 512 + ((key >> 3) & 3) * 128 +
                (dd & 15) * 8 + (key & 7) + 786432;
          } else {
            const int t = key >> 5, g = (key >> 3) & 3, sub = (key >> 2) & 1, jj = key & 3;
            const int frk = g * 4 + jj;
            idx = (size_t)bh * 16384 +
                (((t * 2 + sub) * 2) + (dd >> 5)) * 512 + ((dd >> 3) & 3) * 128 +
                frk * 8 + (dd & 7);
          }
          ((unsigned short*)Cout)[idx] = f2bf(v);
        }
      }
    }
  }
}

// ---------------------------------------------------------------------------
// Fused low-rank attention — no LDS, no barriers, all 16x16x32 MFMA.
// Wave = 16 q-rows; block = 4 waves; grid 64 x 48.
// Swapped QK^T with permuted key-rows: sub-tile C-fragments concatenate
// in-lane into the K=32 PV A-fragment.  Softmax numerics = the verified
// round-5 path (2^-12 floor): max-subtract in log2 domain, exp2f,
// normalize P in f32 BEFORE the RNE bf16 pack.  (Round-7's no-max +
// deferred-norm variant measured 4.6 ulp — reverted.)
// ---------------------------------------------------------------------------
__global__ __launch_bounds__(256) void attn_fused(
    const unsigned short* __restrict__ Qh,   // [4,4096,768] bf16 (pre-scaled)
    const unsigned short* __restrict__ Kf,   // [48][16384] bf16 fragment-major
    const unsigned short* __restrict__ Vf,   // [48][16384] bf16 fragment-major
    unsigned short* __restrict__ ctx)        // [4,4096,768] bf16
{
  const int tid  = threadIdx.x;
  const int lane = tid & 63;
  const int wave = tid >> 6;
  const int bh = blockIdx.y;
  const int b = bh / NH_, h = bh % NH_;
  const int fr = lane & 15;
  const int hi = lane >> 4;
  const int qrow = blockIdx.x * 64 + wave * 16;

  const unsigned short* qp = Qh + (size_t)(b * SEQ_ + qrow + fr) * DIM_ + h * HD_ + hi * 8;
  const bf8 q0 = *(const bf8*)qp;
  const bf8 q1 = *(const bf8*)(qp + 32);

  // ---- QK^T: 8 key-groups of 32
  const unsigned short* kb = Kf + (size_t)bh * 16384 + lane * 8;
  f32x4 scA[8], scB[8];
  __builtin_amdgcn_s_setprio(1);
  #pragma unroll
  for (int s = 0; s < 8; ++s) {
    const bf8 ka0 = *(const bf8*)(kb + (s * 4 + 0) * 512);
    const bf8 ka1 = *(const bf8*)(kb + (s * 4 + 1) * 512);
    const bf8 kb0 = *(const bf8*)(kb + (s * 4 + 2) * 512);
    const bf8 kb1 = *(const bf8*)(kb + (s * 4 + 3) * 512);
    f32x4 x = (f32x4){0.f, 0.f, 0.f, 0.f};
    x = __builtin_amdgcn_mfma_f32_16x16x32_bf16(ka0, q0, x, 0, 0, 0);
    x = __builtin_amdgcn_mfma_f32_16x16x32_bf16(ka1, q1, x, 0, 0, 0);
    scA[s] = x;
    f32x4 y = (f32x4){0.f, 0.f, 0.f, 0.f};
    y = __builtin_amdgcn_mfma_f32_16x16x32_bf16(kb0, q0, y, 0, 0, 0);
    y = __builtin_amdgcn_mfma_f32_16x16x32_bf16(kb1, q1, y, 0, 0, 0);
    scB[s] = y;
  }
  __builtin_amdgcn_s_setprio(0);

  // ---- softmax (round-5 numerics): max over 256 keys of q-column fr
  float m = -1e30f;
  #pragma unroll
  for (int s = 0; s < 8; ++s)
    #pragma unroll
    for (int j = 0; j < 4; ++j) { m = fmaxf(m, scA[s][j]); m = fmaxf(m, scB[s][j]); }
  m = fmaxf(m, __shfl_xor(m, 16));
  m = fmaxf(m, __shfl_xor(m, 32));
  float sum = 0.f;
  #pragma unroll
  for (int s = 0; s < 8; ++s)
    #pragma unroll
    for (int j = 0; j < 4; ++j) {
      const float pa = exp2f(scA[s][j] - m); scA[s][j] = pa; sum += pa;
      const float pb = exp2f(scB[s][j] - m); scB[s][j] = pb; sum += pb;
    }
  sum += __shfl_xor(sum, 16);
  sum += __shfl_xor(sum, 32);
  const float inv = 1.f / sum;

  // ---- pack normalized P (RNE) into K=32 A-fragments
  bf8 pa[8];
  #pragma unroll
  for (int s = 0; s < 8; ++s) {
    bf8 p;
    #pragma unroll
    for (int j = 0; j < 4; ++j) {
      p[j]     = (short)f2bf(scA[s][j] * inv);
      p[4 + j] = (short)f2bf(scB[s][j] * inv);
    }
    pa[s] = p;
  }

  // ---- PV: K=256 as 8 K=32 steps, 4 d-tiles
  const unsigned short* vb = Vf + (size_t)bh * 16384 + lane * 8;
  f32x4 acc[4];
  #pragma unroll
  for (int ct = 0; ct < 4; ++ct) acc[ct] = (f32x4){0.f, 0.f, 0.f, 0.f};
  __builtin_amdgcn_s_setprio(1);
  #pragma unroll
  for (int s = 0; s < 8; ++s) {
    #pragma unroll
    for (int ct = 0; ct < 4; ++ct) {
      const bf8 vf = *(const bf8*)(vb + (s * 4 + ct) * 512);
      acc[ct] = __builtin_amdgcn_mfma_f32_16x16x32_bf16(pa[s], vf, acc[ct], 0, 0, 0);
    }
  }
  __builtin_amdgcn_s_setprio(0);

  // ---- ctx write: lane holds O[q=qrow+hi*4+j][d=h*64+ct*16+fr]
  #pragma unroll
  for (int ct = 0; ct < 4; ++ct)
    #pragma unroll
    for (int j = 0; j < 4; ++j)
      ctx[(size_t)(b * SEQ_ + qrow + hi * 4 + j) * DIM_ + h * HD_ + ct * 16 + fr] =
          f2bf(acc[ct][j]);
}

// ---------------------------------------------------------------------------
extern "C" void kernel_launch(void* const* d_in, const int* in_sizes, int n_in,
                              void* d_out, int out_size, void* d_ws, size_t ws_size,
                              hipStream_t stream) {
  const float* query = (const float*)d_in[0];
  const float* key   = (const float*)d_in[1];
  const float* value = (const float*)d_in[2];
  const float* mask  = (const float*)d_in[3];
  const float* Wq    = (const float*)d_in[4];
  const float* bq    = (const float*)d_in[5];
  const float* Wk    = (const float*)d_in[6];
  const float* bk    = (const float*)d_in[7];
  const float* Wv    = (const float*)d_in[8];
  const float* bv    = (const float*)d_in[9];
  const float* Wo    = (const float*)d_in[10];
  const float* bo    = (const float*)d_in[11];
  float* out = (float*)d_out;

  char* ws = (char*)d_ws;
  unsigned short* Qh  = (unsigned short*)ws;                  // 25,165,824 B
  unsigned short* ctx = (unsigned short*)(ws + 25165824);     // 25,165,824 B
  unsigned short* pK  = (unsigned short*)(ws + 50331648);     //  1,572,864 B
  unsigned short* pV  = (unsigned short*)(ws + 51904512);     //  1,572,864 B (pK+786432 elems)
  unsigned short* Kf  = (unsigned short*)(ws + 53477376);     //  1,572,864 B
  unsigned short* Vf  = (unsigned short*)(ws + 55050240);     //  1,572,864 B (Kf+786432 elems)
  float*          frac = (float*)(ws + 56623104);             //      4,096 B
  unsigned short* Wbf = (unsigned short*)(ws + 56627200);     //  4,718,592 B
  unsigned short* Qbf = ctx;   // ctx region is dead until attn

  const float qscale = 0.125f * LOG2E;   // 1/sqrt(64), e->2 exponent base

  pool_kernel<<<dim3(1024), dim3(384), 0, stream>>>(key, value, mask, pK, pV, frac);
  cvtbf_kernel<<<dim3(7296), dim3(256), 0, stream>>>(query, Wq, Wk, Wv, Wo, Qbf, Wbf);
  gemm_bt<0, 1><<<dim3(768), dim3(256), 0, stream>>>(
      Qbf, Wbf, bq, nullptr, nullptr, Qh, qscale);
  gemm_bt<34, 0><<<dim3(8, 6, 2), dim3(256), 0, stream>>>(
      pK, Wbf + DIM_*DIM_, bk, bv, frac, Kf, 1.f);
  attn_fused<<<dim3(64, 48), dim3(256), 0, stream>>>(Qh, Kf, Vf, ctx);
  gemm_bt<2, 1><<<dim3(768), dim3(256), 0, stream>>>(
      ctx, Wbf + 3*DIM_*DIM_, bo, nullptr, nullptr, out, 1.f);
}